// Round 1
// baseline (161.511 us; speedup 1.0000x reference)
//
#include <hip/hip_runtime.h>
#include <hip/hip_bf16.h>
#include <stdint.h>

typedef short bf16x8 __attribute__((ext_vector_type(8)));
typedef float f32x4 __attribute__((ext_vector_type(4)));
typedef unsigned int u32x2 __attribute__((ext_vector_type(2)));
typedef unsigned int u32x4 __attribute__((ext_vector_type(4)));

#define DI __device__ __forceinline__

// fp32 -> bf16 round-to-nearest-even
DI unsigned short f2bf(float x){
    unsigned u = __builtin_bit_cast(unsigned, x);
    u += 0x7FFFu + ((u >> 16) & 1u);
    return (unsigned short)(u >> 16);
}

__global__ void cast_bf16_kernel(const float* __restrict__ src,
                                 unsigned short* __restrict__ dst, int n4){
    int i = blockIdx.x * 256 + threadIdx.x;
    if (i >= n4) return;
    const float4 v = ((const float4*)src)[i];
    u32x2 o;
    o[0] = (unsigned)f2bf(v.x) | ((unsigned)f2bf(v.y) << 16);
    o[1] = (unsigned)f2bf(v.z) | ((unsigned)f2bf(v.w) << 16);
    ((u32x2*)dst)[i] = o;
}

DI void gld16(const void* g, void* l){
    __builtin_amdgcn_global_load_lds((__attribute__((address_space(1))) void*)g,
                                     (__attribute__((address_space(3))) void*)l,
                                     16, 0, 0);
}

// ---------------- QKV projection GEMM ----------------
// C[m][n] = sum_k X[m][k] * W[n][k]   (both K-major)
// M=4096, N=3072, K=1024; 128x128 tile, BK=32, 4 waves.
__global__ __launch_bounds__(256, 2) void qkv_gemm_kernel(
    const unsigned short* __restrict__ X,   // [4096][1024] bf16
    const unsigned short* __restrict__ W,   // [3072][1024] bf16
    unsigned short* __restrict__ C)         // [4096][3072] bf16
{
    __shared__ char As[128*32*2];
    __shared__ char Bs[128*32*2];
    const int tid = threadIdx.x;
    const int lane = tid & 63;
    const int w   = tid >> 6;
    const int g   = lane >> 4;
    const int l15 = lane & 15;
    const int n0 = blockIdx.x * 128;
    const int m0 = blockIdx.y * 128;
    const int wr = w >> 1, wc = w & 1;

    f32x4 acc[4][4];
    const f32x4 zf = {0.f, 0.f, 0.f, 0.f};
#pragma unroll
    for (int mi = 0; mi < 4; ++mi)
#pragma unroll
        for (int ni = 0; ni < 4; ++ni) acc[mi][ni] = zf;

    // staging chunks: chunk c -> row=c>>2, k8=c&3; thread handles c=tid, tid+256
    const int c0 = tid, c1 = tid + 256;
    const unsigned short* xa0 = X + (m0 + (c0 >> 2)) * 1024 + (c0 & 3) * 8;
    const unsigned short* xa1 = X + (m0 + (c1 >> 2)) * 1024 + (c1 & 3) * 8;
    const unsigned short* wb0 = W + (n0 + (c0 >> 2)) * 1024 + (c0 & 3) * 8;
    const unsigned short* wb1 = W + (n0 + (c1 >> 2)) * 1024 + (c1 & 3) * 8;
    char* aw0 = As + ((tid & 0xFFC0)      ) * 16;
    char* aw1 = As + ((tid & 0xFFC0) + 256) * 16;
    char* bw0 = Bs + ((tid & 0xFFC0)      ) * 16;
    char* bw1 = Bs + ((tid & 0xFFC0) + 256) * 16;

    for (int kt = 0; kt < 32; ++kt){
        const int ko = kt * 32;
        gld16(xa0 + ko, aw0);
        gld16(xa1 + ko, aw1);
        gld16(wb0 + ko, bw0);
        gld16(wb1 + ko, bw1);
        __syncthreads();
        bf16x8 af[4], bfr[4];
#pragma unroll
        for (int mi = 0; mi < 4; ++mi)
            af[mi] = *(const bf16x8*)(As + ((wr*64 + mi*16 + l15)*32 + g*8)*2);
#pragma unroll
        for (int ni = 0; ni < 4; ++ni)
            bfr[ni] = *(const bf16x8*)(Bs + ((wc*64 + ni*16 + l15)*32 + g*8)*2);
#pragma unroll
        for (int mi = 0; mi < 4; ++mi)
#pragma unroll
            for (int ni = 0; ni < 4; ++ni)
                acc[mi][ni] = __builtin_amdgcn_mfma_f32_16x16x32_bf16(
                    af[mi], bfr[ni], acc[mi][ni], 0, 0, 0);
        __syncthreads();
    }
#pragma unroll
    for (int mi = 0; mi < 4; ++mi)
#pragma unroll
        for (int ni = 0; ni < 4; ++ni){
            const int row = m0 + wr*64 + mi*16 + g*4;
            const int col = n0 + wc*64 + ni*16 + l15;
#pragma unroll
            for (int r = 0; r < 4; ++r)
                C[(row + r) * 3072 + col] = f2bf(acc[mi][ni][r]);
        }
}

// ---------------- causal flash attention ----------------
// QBLK=64 (4 waves x 16 q rows), KVBLK=64, hd=128, swapped QK^T.
static constexpr float SOFT_C = 0.08838834764831845f * 1.4426950408889634f; // log2(e)/sqrt(128)

__global__ __launch_bounds__(256, 2) void attn_kernel(
    const unsigned short* __restrict__ QKV,  // [4096][3072] bf16
    float* __restrict__ out)                 // [4096][1024] fp32
{
    __shared__ char Ks[2][16384];   // K [kv=64][d=128], swizzled
    __shared__ char Vs[2][16384];   // V^T [d=128][kv=64], swizzled
    __shared__ char Ps[4][2048];    // per-wave P [q=16][kv=64], swizzled

    const int tid = threadIdx.x;
    const int lane = tid & 63;
    const int w   = tid >> 6;
    const int g   = lane >> 4;
    const int l15 = lane & 15;
    const int bid = blockIdx.x;
    const int h   = bid & 7;
    const int qb  = 63 - (bid >> 3);     // longest blocks first
    const int q0  = qb * 64;
    const int q0w = q0 + w * 16;
    const int nkvb = qb + 1;

    const unsigned short* Qp = QKV + h * 128;
    const unsigned short* Kp = QKV + 1024 + h * 128;
    const unsigned short* Vp = QKV + 2048 + h * 128;

    // Q fragments in registers: lane holds Q[q0w+l15][dc*32 + g*8 .. +8]
    bf16x8 qf[4];
#pragma unroll
    for (int dc = 0; dc < 4; ++dc)
        qf[dc] = *(const bf16x8*)(Qp + (q0w + l15) * 3072 + dc*32 + g*8);

    f32x4 oacc[8];
    const f32x4 zf = {0.f, 0.f, 0.f, 0.f};
#pragma unroll
    for (int dt = 0; dt < 8; ++dt) oacc[dt] = zf;
    float m_run = -__builtin_inff();
    float lsum = 0.f;

    // staging registers (next KV block)
    bf16x8 kreg[4], vreg[4];
    const int st_d8 = tid & 15;          // d-chunk (8 elems)
    const int st_kv = tid >> 4;          // K: row base; V: kv quad

    {   // prologue: load kv-block 0
#pragma unroll
        for (int t = 0; t < 4; ++t)
            kreg[t] = *(const bf16x8*)(Kp + (st_kv + 16*t) * 3072 + st_d8 * 8);
#pragma unroll
        for (int j = 0; j < 4; ++j)
            vreg[j] = *(const bf16x8*)(Vp + (st_kv*4 + j) * 3072 + st_d8 * 8);
    }

    int buf = 0;
    for (int i = 0; i < nkvb; ++i){
        // ---- write staged regs to LDS ----
        {
            char* Kb = Ks[buf];
#pragma unroll
            for (int t = 0; t < 4; ++t){
                const int kv = st_kv + 16*t;
                int addr = kv*256 + st_d8*16;
                addr ^= ((kv & 7) << 4);
                *(bf16x8*)(Kb + addr) = kreg[t];
            }
            char* Vb = Vs[buf];
#pragma unroll
            for (int e = 0; e < 8; ++e){
                const unsigned lo = (unsigned)(unsigned short)vreg[0][e]
                                  | ((unsigned)(unsigned short)vreg[1][e] << 16);
                const unsigned hi = (unsigned)(unsigned short)vreg[2][e]
                                  | ((unsigned)(unsigned short)vreg[3][e] << 16);
                const int d = st_d8*8 + e;
                int addr = d*128 + st_kv*8;
                addr ^= ((((addr >> 7) ^ (addr >> 10)) & 7) << 4);
                u32x2 val; val[0] = lo; val[1] = hi;
                *(u32x2*)(Vb + addr) = val;
            }
        }
        __syncthreads();

        // ---- issue next block's global loads (hidden under compute) ----
        if (i + 1 < nkvb){
            const int kv0n = (i + 1) * 64;
#pragma unroll
            for (int t = 0; t < 4; ++t)
                kreg[t] = *(const bf16x8*)(Kp + (kv0n + st_kv + 16*t) * 3072 + st_d8 * 8);
#pragma unroll
            for (int j = 0; j < 4; ++j)
                vreg[j] = *(const bf16x8*)(Vp + (kv0n + st_kv*4 + j) * 3072 + st_d8 * 8);
        }

        // ---- S^T = K · Q^T : D[kv][q], lane owns q=l15 column ----
        const int kv0 = i * 64;
        char* Kb = Ks[buf];
        char* Vb = Vs[buf];
        char* Pw = Ps[w];

        f32x4 sacc[4];
#pragma unroll
        for (int t = 0; t < 4; ++t) sacc[t] = zf;
#pragma unroll
        for (int dc = 0; dc < 4; ++dc){
            bf16x8 kf[4];
#pragma unroll
            for (int t = 0; t < 4; ++t){
                const int kv = l15 + 16*t;
                int addr = kv*256 + dc*64 + g*16;
                addr ^= ((kv & 7) << 4);
                kf[t] = *(const bf16x8*)(Kb + addr);
            }
#pragma unroll
            for (int t = 0; t < 4; ++t)
                sacc[t] = __builtin_amdgcn_mfma_f32_16x16x32_bf16(
                    kf[t], qf[dc], sacc[t], 0, 0, 0);
        }

        // causal mask (only the diagonal = last kv block)
        if (i == nkvb - 1){
            const int qg = q0w + l15;
#pragma unroll
            for (int t = 0; t < 4; ++t)
#pragma unroll
                for (int r = 0; r < 4; ++r){
                    const int kvg = kv0 + 16*t + 4*g + r;
                    if (kvg > qg) sacc[t][r] = -__builtin_inff();
                }
        }

        // ---- online softmax for row q=l15 (in-lane + 2 shfl) ----
        float rmax = sacc[0][0];
#pragma unroll
        for (int t = 0; t < 4; ++t)
#pragma unroll
            for (int r = 0; r < 4; ++r) rmax = fmaxf(rmax, sacc[t][r]);
        rmax = fmaxf(rmax, __shfl_xor(rmax, 16));
        rmax = fmaxf(rmax, __shfl_xor(rmax, 32));
        const float mnew = fmaxf(m_run, rmax);
        const float fold = exp2f((m_run - mnew) * SOFT_C);
        m_run = mnew;
        float rs = 0.f;
#pragma unroll
        for (int t = 0; t < 4; ++t)
#pragma unroll
            for (int r = 0; r < 4; ++r){
                const float p = exp2f((sacc[t][r] - mnew) * SOFT_C);
                sacc[t][r] = p;
                rs += p;
            }
        rs += __shfl_xor(rs, 16);
        rs += __shfl_xor(rs, 32);
        lsum = lsum * fold + rs;

        // rescale O (rows q=4g+r): fetch factor from lane 4g+r
#pragma unroll
        for (int r = 0; r < 4; ++r){
            const float fo = __shfl(fold, 4*g + r);
#pragma unroll
            for (int dt = 0; dt < 8; ++dt) oacc[dt][r] *= fo;
        }

        // ---- pack P (bf16) into per-wave LDS ----
#pragma unroll
        for (int t = 0; t < 4; ++t){
            const unsigned lo = (unsigned)f2bf(sacc[t][0]) | ((unsigned)f2bf(sacc[t][1]) << 16);
            const unsigned hi = (unsigned)f2bf(sacc[t][2]) | ((unsigned)f2bf(sacc[t][3]) << 16);
            int addr = l15*128 + 32*t + 8*g;
            addr ^= (((addr >> 7) & 7) << 4);
            u32x2 val; val[0] = lo; val[1] = hi;
            *(u32x2*)(Pw + addr) = val;
        }

        // ---- O += P · V ----
#pragma unroll
        for (int kc = 0; kc < 2; ++kc){
            int paddr = l15*128 + 64*kc + 16*g;
            paddr ^= (((paddr >> 7) & 7) << 4);
            const bf16x8 pa = *(const bf16x8*)(Pw + paddr);
#pragma unroll
            for (int dt = 0; dt < 8; ++dt){
                const int d = l15 + 16*dt;
                int addr = d*128 + 64*kc + 16*g;
                addr ^= ((((addr >> 7) ^ (addr >> 10)) & 7) << 4);
                const bf16x8 vb = *(const bf16x8*)(Vb + addr);
                oacc[dt] = __builtin_amdgcn_mfma_f32_16x16x32_bf16(pa, vb, oacc[dt], 0, 0, 0);
            }
        }
        buf ^= 1;
    }

    // ---- epilogue: divide by lsum, store fp32 ----
    float inv[4];
#pragma unroll
    for (int r = 0; r < 4; ++r) inv[r] = 1.0f / __shfl(lsum, 4*g + r);
#pragma unroll
    for (int dt = 0; dt < 8; ++dt)
#pragma unroll
        for (int r = 0; r < 4; ++r){
            const int row = q0w + 4*g + r;
            out[row * 1024 + h * 128 + dt*16 + l15] = oacc[dt][r] * inv[r];
        }
}

extern "C" void kernel_launch(void* const* d_in, const int* in_sizes, int n_in,
                              void* d_out, int out_size, void* d_ws, size_t ws_size,
                              hipStream_t stream){
    const float* X  = (const float*)d_in[0];
    const float* Wq = (const float*)d_in[1];
    const float* Wk = (const float*)d_in[2];
    const float* Wv = (const float*)d_in[3];

    unsigned short* Xb  = (unsigned short*)d_ws;        // 4096*1024 bf16
    unsigned short* Wb  = Xb + 4096*1024;               // 3072*1024 bf16 (Wq|Wk|Wv rows)
    unsigned short* QKV = Wb + 3072*1024;               // 4096*3072 bf16
    float* outp = (float*)d_out;

    cast_bf16_kernel<<<4096, 256, 0, stream>>>(X,  Xb, 4096*1024/4);
    cast_bf16_kernel<<<1024, 256, 0, stream>>>(Wq, Wb,               1024*1024/4);
    cast_bf16_kernel<<<1024, 256, 0, stream>>>(Wk, Wb + 1024*1024,   1024*1024/4);
    cast_bf16_kernel<<<1024, 256, 0, stream>>>(Wv, Wb + 2*1024*1024, 1024*1024/4);

    qkv_gemm_kernel<<<dim3(24, 32), 256, 0, stream>>>(Xb, Wb, QKV);
    attn_kernel<<<512, 256, 0, stream>>>(QKV, outp);
}

// Round 3
// 154.665 us; speedup vs baseline: 1.0443x; 1.0443x over previous
//
#include <hip/hip_runtime.h>
#include <hip/hip_bf16.h>
#include <stdint.h>

typedef short bf16x8 __attribute__((ext_vector_type(8)));
typedef float f32x4 __attribute__((ext_vector_type(4)));
typedef unsigned int u32x2 __attribute__((ext_vector_type(2)));

#define DI __device__ __forceinline__

// fp32 -> bf16 round-to-nearest-even
DI unsigned short f2bf(float x){
    unsigned u = __builtin_bit_cast(unsigned, x);
    u += 0x7FFFu + ((u >> 16) & 1u);
    return (unsigned short)(u >> 16);
}

__global__ void cast_bf16_kernel(const float* __restrict__ src,
                                 unsigned short* __restrict__ dst, int n4){
    int i = blockIdx.x * 256 + threadIdx.x;
    if (i >= n4) return;
    const float4 v = ((const float4*)src)[i];
    u32x2 o;
    o[0] = (unsigned)f2bf(v.x) | ((unsigned)f2bf(v.y) << 16);
    o[1] = (unsigned)f2bf(v.z) | ((unsigned)f2bf(v.w) << 16);
    ((u32x2*)dst)[i] = o;
}

DI void gld16(const void* g, void* l){
    __builtin_amdgcn_global_load_lds((__attribute__((address_space(1))) void*)g,
                                     (__attribute__((address_space(3))) void*)l,
                                     16, 0, 0);
}

// ---------------- QKV projection GEMM ----------------
// C[m][n] = sum_k X[m][k] * W[n][k]   (both K-major)
// M=4096, N=3072, K=1024; 128x128 tile, BK=32, 4 waves.  (round-1 verified)
__global__ __launch_bounds__(256, 2) void qkv_gemm_kernel(
    const unsigned short* __restrict__ X,   // [4096][1024] bf16
    const unsigned short* __restrict__ W,   // [3072][1024] bf16
    unsigned short* __restrict__ C)         // [4096][3072] bf16
{
    __shared__ char As[128*32*2];
    __shared__ char Bs[128*32*2];
    const int tid = threadIdx.x;
    const int lane = tid & 63;
    const int w   = tid >> 6;
    const int g   = lane >> 4;
    const int l15 = lane & 15;
    const int n0 = blockIdx.x * 128;
    const int m0 = blockIdx.y * 128;
    const int wr = w >> 1, wc = w & 1;

    f32x4 acc[4][4];
    const f32x4 zf = {0.f, 0.f, 0.f, 0.f};
#pragma unroll
    for (int mi = 0; mi < 4; ++mi)
#pragma unroll
        for (int ni = 0; ni < 4; ++ni) acc[mi][ni] = zf;

    const int c0 = tid, c1 = tid + 256;
    const unsigned short* xa0 = X + (m0 + (c0 >> 2)) * 1024 + (c0 & 3) * 8;
    const unsigned short* xa1 = X + (m0 + (c1 >> 2)) * 1024 + (c1 & 3) * 8;
    const unsigned short* wb0 = W + (n0 + (c0 >> 2)) * 1024 + (c0 & 3) * 8;
    const unsigned short* wb1 = W + (n0 + (c1 >> 2)) * 1024 + (c1 & 3) * 8;
    char* aw0 = As + ((tid & 0xFFC0)      ) * 16;
    char* aw1 = As + ((tid & 0xFFC0) + 256) * 16;
    char* bw0 = Bs + ((tid & 0xFFC0)      ) * 16;
    char* bw1 = Bs + ((tid & 0xFFC0) + 256) * 16;

    for (int kt = 0; kt < 32; ++kt){
        const int ko = kt * 32;
        gld16(xa0 + ko, aw0);
        gld16(xa1 + ko, aw1);
        gld16(wb0 + ko, bw0);
        gld16(wb1 + ko, bw1);
        __syncthreads();
        bf16x8 af[4], bfr[4];
#pragma unroll
        for (int mi = 0; mi < 4; ++mi)
            af[mi] = *(const bf16x8*)(As + ((wr*64 + mi*16 + l15)*32 + g*8)*2);
#pragma unroll
        for (int ni = 0; ni < 4; ++ni)
            bfr[ni] = *(const bf16x8*)(Bs + ((wc*64 + ni*16 + l15)*32 + g*8)*2);
#pragma unroll
        for (int mi = 0; mi < 4; ++mi)
#pragma unroll
            for (int ni = 0; ni < 4; ++ni)
                acc[mi][ni] = __builtin_amdgcn_mfma_f32_16x16x32_bf16(
                    af[mi], bfr[ni], acc[mi][ni], 0, 0, 0);
        __syncthreads();
    }
#pragma unroll
    for (int mi = 0; mi < 4; ++mi)
#pragma unroll
        for (int ni = 0; ni < 4; ++ni){
            const int row = m0 + wr*64 + mi*16 + g*4;
            const int col = n0 + wc*64 + ni*16 + l15;
#pragma unroll
            for (int r = 0; r < 4; ++r)
                C[(row + r) * 3072 + col] = f2bf(acc[mi][ni][r]);
        }
}

// ---------------- causal flash attention ----------------
// QBLK=64 (4 waves x 16 q rows), KVBLK=64, hd=128.
// Swapped QK^T (S^T), O^T PV form (own-lane softmax state), shfl_xor reduce.
static constexpr float SOFT_C = 0.08838834764831845f * 1.4426950408889634f; // log2(e)/sqrt(128)

__global__ __launch_bounds__(256, 2) void attn_kernel(
    const unsigned short* __restrict__ QKV,  // [4096][3072] bf16
    float* __restrict__ out)                 // [4096][1024] fp32
{
    __shared__ char Ks[2][16384];   // K [kv=64][d=128], slot ^= kv&15
    __shared__ char Vs[2][16384];   // V^T packed: row R holds d=2R,2R+1; slot ^= (R^(R>>4))&15
    __shared__ char Ps[4][2048];    // per-wave P [q=16][kv=64], slot ^= l15&7

    const int tid = threadIdx.x;
    const int lane = tid & 63;
    const int w   = tid >> 6;
    const int g   = lane >> 4;
    const int l15 = lane & 15;
    const int bid = blockIdx.x;
    const int h   = bid & 7;
    const int r_  = bid >> 3;
    // pairing: blocks b and b+256 get qb summing to 63 -> ~uniform per-CU work
    const int qb  = (r_ < 32) ? (63 - r_) : (r_ - 32);
    const int q0w = qb * 64 + w * 16;
    const int nkvb = qb + 1;

    const unsigned short* Qp = QKV + h * 128;
    const unsigned short* Kp = QKV + 1024 + h * 128;
    const unsigned short* Vp = QKV + 2048 + h * 128;

    // Q fragments: lane holds Q[q0w+l15][dc*32 + g*8 .. +8]
    bf16x8 qf[4];
#pragma unroll
    for (int dc = 0; dc < 4; ++dc)
        qf[dc] = *(const bf16x8*)(Qp + (q0w + l15) * 3072 + dc*32 + g*8);

    f32x4 oaccT[8];
    const f32x4 zf = {0.f, 0.f, 0.f, 0.f};
#pragma unroll
    for (int dt = 0; dt < 8; ++dt) oaccT[dt] = zf;
    float m_run = -__builtin_inff();
    float lsum = 0.f;

    // staging: thread (st_d8, st_kv)
    const int st_d8 = tid & 15;
    const int st_kv = tid >> 4;
    const unsigned short* kbase = Kp + st_kv * 3072 + st_d8 * 8;
    const unsigned short* vbase = Vp + (st_kv*4) * 3072 + st_d8 * 8;

    bf16x8 kreg[4], vreg[4];
#pragma unroll
    for (int t = 0; t < 4; ++t) kreg[t] = *(const bf16x8*)(kbase + 16*t*3072);
#pragma unroll
    for (int j = 0; j < 4; ++j) vreg[j] = *(const bf16x8*)(vbase + j*3072);

    const int kw_addr = st_kv*256 + ((st_d8 ^ st_kv) << 4);   // K write base

    int buf = 0;
    for (int i = 0; i < nkvb; ++i){
        char* Kb = Ks[buf];
        char* Vb = Vs[buf];
        char* Pw = Ps[w];

        // ---- write staged regs to LDS ----
#pragma unroll
        for (int t = 0; t < 4; ++t)
            *(bf16x8*)(Kb + kw_addr + t*4096) = kreg[t];
#pragma unroll
        for (int e = 0; e < 8; ++e){
            const int R = st_d8*4 + (e >> 1);               // d = st_d8*8+e, R = d>>1
            const int slot = ((e & 1) << 3) + (st_kv >> 1);
            const int s = (R ^ (R >> 4)) & 15;
            u32x2 val;
            val[0] = (unsigned)(unsigned short)vreg[0][e] | ((unsigned)(unsigned short)vreg[1][e] << 16);
            val[1] = (unsigned)(unsigned short)vreg[2][e] | ((unsigned)(unsigned short)vreg[3][e] << 16);
            *(u32x2*)(Vb + R*256 + ((slot ^ s) << 4) + ((st_kv & 1) << 3)) = val;
        }
        __syncthreads();

        // ---- issue next block's global loads (in flight under compute) ----
        if (i + 1 < nkvb){
            const unsigned short* kn = kbase + (size_t)(i+1)*64*3072;
            const unsigned short* vn = vbase + (size_t)(i+1)*64*3072;
#pragma unroll
            for (int t = 0; t < 4; ++t) kreg[t] = *(const bf16x8*)(kn + 16*t*3072);
#pragma unroll
            for (int j = 0; j < 4; ++j) vreg[j] = *(const bf16x8*)(vn + j*3072);
        }

        // ---- S^T = K · Q^T : lane owns column q = l15 ----
        f32x4 sacc[4];
#pragma unroll
        for (int t = 0; t < 4; ++t) sacc[t] = zf;
        __builtin_amdgcn_s_setprio(1);
#pragma unroll
        for (int dc = 0; dc < 4; ++dc){
            bf16x8 kf[4];
#pragma unroll
            for (int t = 0; t < 4; ++t)
                kf[t] = *(const bf16x8*)(Kb + (16*t + l15)*256 + (((4*dc + g) ^ l15) << 4));
#pragma unroll
            for (int t = 0; t < 4; ++t)
                sacc[t] = __builtin_amdgcn_mfma_f32_16x16x32_bf16(
                    kf[t], qf[dc], sacc[t], 0, 0, 0);
        }
        __builtin_amdgcn_s_setprio(0);

        // causal mask (diagonal block only)
        if (i == nkvb - 1){
            const int qg = q0w + l15;
            const int kv0 = i * 64;
#pragma unroll
            for (int t = 0; t < 4; ++t)
#pragma unroll
                for (int r = 0; r < 4; ++r){
                    const int kvg = kv0 + 16*t + 4*g + r;
                    if (kvg > qg) sacc[t][r] = -__builtin_inff();
                }
        }

        // ---- online softmax for column q=l15 (in-lane + shfl_xor butterflies) ----
        float rmax = sacc[0][0];
#pragma unroll
        for (int t = 0; t < 4; ++t)
#pragma unroll
            for (int r = 0; r < 4; ++r) rmax = fmaxf(rmax, sacc[t][r]);
        rmax = fmaxf(rmax, __shfl_xor(rmax, 16));
        rmax = fmaxf(rmax, __shfl_xor(rmax, 32));
        const float mnew = fmaxf(m_run, rmax);
        const float fold = exp2f((m_run - mnew) * SOFT_C);
        m_run = mnew;
        float rs = 0.f;
#pragma unroll
        for (int t = 0; t < 4; ++t)
#pragma unroll
            for (int r = 0; r < 4; ++r){
                const float p = exp2f((sacc[t][r] - mnew) * SOFT_C);
                sacc[t][r] = p;
                rs += p;
            }
        rs += __shfl_xor(rs, 16);
        rs += __shfl_xor(rs, 32);
        lsum = lsum * fold + rs;

        // rescale O^T: every element of this lane has q = l15 -> own-lane factor
#pragma unroll
        for (int dt = 0; dt < 8; ++dt) oaccT[dt] *= fold;

        // ---- pack P (bf16) into per-wave LDS: row q=l15, logical byte = kv*2 ----
#pragma unroll
        for (int t = 0; t < 4; ++t){
            u32x2 val;
            val[0] = (unsigned)f2bf(sacc[t][0]) | ((unsigned)f2bf(sacc[t][1]) << 16);
            val[1] = (unsigned)f2bf(sacc[t][2]) | ((unsigned)f2bf(sacc[t][3]) << 16);
            *(u32x2*)(Pw + l15*128 + ((32*t + 8*g) ^ ((l15 & 7) << 4))) = val;
        }

        // ---- O^T += V^T · P^T : D[d_local][q=l15] ----
        __builtin_amdgcn_s_setprio(1);
#pragma unroll
        for (int c = 0; c < 2; ++c){
            const bf16x8 pfrag = *(const bf16x8*)(Pw + l15*128 + ((64*c + 16*g) ^ ((l15 & 7) << 4)));
#pragma unroll
            for (int dt = 0; dt < 8; ++dt){
                const int R = 8*dt + (l15 >> 1);            // d = 16*dt + l15, R = d>>1
                const int slot = ((l15 & 1) << 3) + 4*c + g;
                const int s = (R ^ (R >> 4)) & 15;
                const bf16x8 vfrag = *(const bf16x8*)(Vb + R*256 + ((slot ^ s) << 4));
                oaccT[dt] = __builtin_amdgcn_mfma_f32_16x16x32_bf16(
                    vfrag, pfrag, oaccT[dt], 0, 0, 0);
            }
        }
        __builtin_amdgcn_s_setprio(0);
        buf ^= 1;
    }

    // ---- epilogue: divide by own-lane lsum, float4 stores ----
    const float inv = 1.0f / lsum;
    float* orow = out + (q0w + l15) * 1024 + h * 128;
#pragma unroll
    for (int dt = 0; dt < 8; ++dt){
        f32x4 o = oaccT[dt] * inv;
        *(f32x4*)(orow + dt*16 + g*4) = o;
    }
}

extern "C" void kernel_launch(void* const* d_in, const int* in_sizes, int n_in,
                              void* d_out, int out_size, void* d_ws, size_t ws_size,
                              hipStream_t stream){
    const float* X  = (const float*)d_in[0];
    const float* Wq = (const float*)d_in[1];
    const float* Wk = (const float*)d_in[2];
    const float* Wv = (const float*)d_in[3];

    unsigned short* Xb  = (unsigned short*)d_ws;        // 4096*1024 bf16
    unsigned short* Wb  = Xb + 4096*1024;               // 3072*1024 bf16 (Wq|Wk|Wv rows)
    unsigned short* QKV = Wb + 3072*1024;               // 4096*3072 bf16
    float* outp = (float*)d_out;

    cast_bf16_kernel<<<4096, 256, 0, stream>>>(X,  Xb, 4096*1024/4);
    cast_bf16_kernel<<<1024, 256, 0, stream>>>(Wq, Wb,               1024*1024/4);
    cast_bf16_kernel<<<1024, 256, 0, stream>>>(Wk, Wb + 1024*1024,   1024*1024/4);
    cast_bf16_kernel<<<1024, 256, 0, stream>>>(Wv, Wb + 2*1024*1024, 1024*1024/4);

    qkv_gemm_kernel<<<dim3(24, 32), 256, 0, stream>>>(Xb, Wb, QKV);
    attn_kernel<<<512, 256, 0, stream>>>(QKV, outp);
}